// Round 2
// baseline (615.534 us; speedup 1.0000x reference)
//
#include <hip/hip_runtime.h>
#include <hip/hip_bf16.h>

typedef float f32x4 __attribute__((ext_vector_type(4)));
typedef __bf16 bf16x8 __attribute__((ext_vector_type(8)));

#define N_IMG 32
#define C_IN  256
#define HW    56
#define OC_N  256
#define N_X   (N_IMG * C_IN * HW * HW)      // 25690112 x elems == out elems
#define HP    58
#define WPAD  68

static constexpr size_t WQ_OFF  = 8192;                 // bf16[256][2304]
static constexpr size_t XP_OFF  = 2097152;              // bf16[32][58][68][256]
static constexpr size_t XP_ELEMS = (size_t)N_IMG * HP * WPAD * C_IN;

// header (float/uint indices into ws):
// [0] xmin_enc  [1] xmax_enc  [2] in_scale  [3] zp
// [4..19]  dynmax_enc per bit value (raw nonneg-float bit pattern)
// [64..319]  b_int per oc
// [320..575] Moc per oc
// [576..831] lo per oc
// [832..1087] hi per oc

__device__ __forceinline__ unsigned enc_f(float f) {
    unsigned u = __float_as_uint(f);
    return (u & 0x80000000u) ? ~u : (u | 0x80000000u);
}
__device__ __forceinline__ float dec_f(unsigned u) {
    u = (u & 0x80000000u) ? (u & 0x7FFFFFFFu) : ~u;
    return __uint_as_float(u);
}

__global__ void k_init(unsigned* hdr) {
    int t = threadIdx.x;
    if (t == 0) hdr[0] = 0xFFFFFFFFu;   // min over encoded
    if (t == 1) hdr[1] = 0u;            // max over encoded
    if (t >= 4 && t < 20) hdr[t] = 0u;  // dynmax
}

__global__ __launch_bounds__(256) void k_minmax(const float4* __restrict__ x4, int n4, unsigned* hdr) {
    float mn = INFINITY, mx = -INFINITY;
    for (int i = blockIdx.x * blockDim.x + threadIdx.x; i < n4; i += gridDim.x * blockDim.x) {
        float4 v = x4[i];
        mn = fminf(mn, fminf(fminf(v.x, v.y), fminf(v.z, v.w)));
        mx = fmaxf(mx, fmaxf(fmaxf(v.x, v.y), fmaxf(v.z, v.w)));
    }
    for (int s = 32; s; s >>= 1) {
        mn = fminf(mn, __shfl_xor(mn, s));
        mx = fmaxf(mx, __shfl_xor(mx, s));
    }
    __shared__ float smn[4], smx[4];
    int l = threadIdx.x & 63, wv = threadIdx.x >> 6;
    if (l == 0) { smn[wv] = mn; smx[wv] = mx; }
    __syncthreads();
    if (threadIdx.x == 0) {
        mn = fminf(fminf(smn[0], smn[1]), fminf(smn[2], smn[3]));
        mx = fmaxf(fmaxf(smx[0], smx[1]), fmaxf(smx[2], smx[3]));
        atomicMin(&hdr[0], enc_f(mn));
        atomicMax(&hdr[1], enc_f(mx));
    }
}

__global__ void k_scalars(unsigned* hdr) {
    float xmin = dec_f(hdr[0]), xmax = dec_f(hdr[1]);
    float in_scale = (xmax - xmin) / 255.0f;          // (qa_max-qa_min)=255
    float zp = rintf(-128.0f - xmin / in_scale);
    ((float*)hdr)[2] = in_scale;
    ((float*)hdr)[3] = zp;
}

// one block per output channel; 256 threads = one per input channel (9 taps each)
__global__ __launch_bounds__(256) void k_wquant(const float* __restrict__ weight,
                                                const float* __restrict__ bias,
                                                const int* __restrict__ bits,
                                                char* ws) {
    float* hf = (float*)ws;
    __hip_bfloat16* Wq = (__hip_bfloat16*)(ws + WQ_OFF);
    int oc = blockIdx.x, tid = threadIdx.x;
    const float* wp = weight + ((size_t)oc * 256 + tid) * 9;
    float w9[9];
    float wm = 0.0f;
#pragma unroll
    for (int t = 0; t < 9; ++t) { w9[t] = wp[t]; wm = fmaxf(wm, fabsf(w9[t])); }
    for (int s = 32; s; s >>= 1) wm = fmaxf(wm, __shfl_xor(wm, s));
    __shared__ float red[4];
    __shared__ float s_wsc;
    int l = tid & 63, wv = tid >> 6;
    if (l == 0) red[wv] = wm;
    __syncthreads();
    int b = bits[oc];
    if (tid == 0) {
        float wmax = fmaxf(fmaxf(red[0], red[1]), fmaxf(red[2], red[3]));
        float qd = (float)((1 << b) - 1);                      // qw_max - qw_min
        float wsc = fmaxf(wmax * 2.0f / qd, 1e-9f);
        s_wsc = wsc;
        float in_scale = hf[2];
        hf[64 + oc] = rintf(bias[oc] / (in_scale * wsc));      // b_int
    }
    __syncthreads();
    float wsc = s_wsc;
    float qmax = (float)((1 << (b - 1)) - 1);
    float qmin = -(float)(1 << (b - 1));
    size_t base = (size_t)oc * 2304;
#pragma unroll
    for (int t = 0; t < 9; ++t) {
        float q = rintf(w9[t] / wsc);
        q = fminf(fmaxf(q, qmin), qmax);
        Wq[base + t * 256 + tid] = __float2bfloat16(q);        // layout [oc][tap*256+c]
    }
}

// quantize x and transpose NCHW -> padded channel-last [n][hp][wp][c] bf16
__global__ __launch_bounds__(256) void k_quantx(const float* __restrict__ x, char* ws) {
    const float* hf = (const float*)ws;
    float in_scale = hf[2], zp = hf[3];
    __hip_bfloat16* Xp = (__hip_bfloat16*)(ws + XP_OFF);
    int w0 = blockIdx.x * 8, h = blockIdx.y, n = blockIdx.z;
    int tid = threadIdx.x;
    __shared__ float tx[32][9];
    int wA = tid & 7, cA = tid >> 3;     // read phase: 32 c x 8 w
    int cB = tid & 31, wB = tid >> 5;    // write phase: 8 w x 32 c (c fastest)
    for (int cc = 0; cc < 256; cc += 32) {
        float v = x[(((size_t)n * 256 + cc + cA) * 56 + h) * 56 + w0 + wA];
        float xi = rintf(v / in_scale + zp);
        xi = fminf(fmaxf(xi, -128.0f), 127.0f);
        tx[cA][wA] = xi - zp;
        __syncthreads();
        Xp[(((size_t)n * HP + h + 1) * WPAD + (w0 + wB + 1)) * 256 + cc + cB] =
            __float2bfloat16(tx[cB][wB]);
        __syncthreads();
    }
}

// implicit-GEMM conv: one workgroup per (n,h); 256 oc x 64 px tile; 4 waves
__global__ __launch_bounds__(256) void k_conv(const int* __restrict__ bits,
                                              float* __restrict__ out, char* ws) {
    const float* hf = (const float*)ws;
    unsigned* hdr = (unsigned*)ws;
    const __hip_bfloat16* Xp = (const __hip_bfloat16*)(ws + XP_OFF);
    const bf16x8* wq8 = (const bf16x8*)(ws + WQ_OFF);

    int wg = blockIdx.x;
    int n = wg / 56, h = wg % 56;
    int tid = threadIdx.x;
    int wv = tid >> 6, l = tid & 63;
    int l15 = l & 15, lq = l >> 4;

    __shared__ alignas(16) __hip_bfloat16 Xs[66 * 40];   // [wp 0..65][c-chunk 32, pad->40]
    __shared__ unsigned sdyn[16];
    if (tid < 16) sdyn[tid] = 0;

    f32x4 acc[4][4];
#pragma unroll
    for (int i = 0; i < 4; ++i)
#pragma unroll
        for (int j = 0; j < 4; ++j) acc[i][j] = (f32x4){0.f, 0.f, 0.f, 0.f};

    int sq = tid & 3, swp = tid >> 2;    // staging: 64 wp x (4x8 c)

    for (int dh = 0; dh < 3; ++dh) {
        const __hip_bfloat16* rowp = Xp + (size_t)(n * HP + h + dh) * WPAD * 256;
        for (int cc = 0; cc < 256; cc += 32) {
            __syncthreads();
            *(uint4*)&Xs[swp * 40 + sq * 8] = *(const uint4*)&rowp[swp * 256 + cc + sq * 8];
            if (tid < 8) {
                int wp2 = 64 + (tid >> 2), q2 = tid & 3;
                *(uint4*)&Xs[wp2 * 40 + q2 * 8] = *(const uint4*)&rowp[wp2 * 256 + cc + q2 * 8];
            }
            __syncthreads();
#pragma unroll
            for (int dw = 0; dw < 3; ++dw) {
                int t = dh * 3 + dw;
                bf16x8 af[4];
#pragma unroll
                for (int i = 0; i < 4; ++i) {
                    int oc = wv * 64 + i * 16 + l15;
                    af[i] = wq8[(size_t)oc * 288 + t * 32 + (cc >> 3) + lq];
                }
#pragma unroll
                for (int j = 0; j < 4; ++j) {
                    bf16x8 bv = *(const bf16x8*)&Xs[(j * 16 + l15 + dw) * 40 + lq * 8];
#pragma unroll
                    for (int i = 0; i < 4; ++i)
                        acc[i][j] = __builtin_amdgcn_mfma_f32_16x16x32_bf16(af[i], bv, acc[i][j], 0, 0, 0);
                }
            }
        }
    }
    __syncthreads();

    // epilogue: + b_int, store, per-group max|acc|
#pragma unroll
    for (int i = 0; i < 4; ++i) {
#pragma unroll
        for (int r = 0; r < 4; ++r) {
            int oc = wv * 64 + i * 16 + lq * 4 + r;
            float bi = hf[64 + oc];
            float m = 0.0f;
#pragma unroll
            for (int j = 0; j < 4; ++j) {
                int w = j * 16 + l15;
                float v = acc[i][j][r] + bi;
                if (w < 56) {
                    out[(((size_t)n * 256 + oc) * 56 + h) * 56 + w] = v;
                    m = fmaxf(m, fabsf(v));
                }
            }
#pragma unroll
            for (int s = 1; s < 16; s <<= 1) m = fmaxf(m, __shfl_xor(m, s));
            if (l15 == 0) atomicMax(&sdyn[bits[oc] & 15], __float_as_uint(m));
        }
    }
    __syncthreads();
    if (tid < 16 && sdyn[tid]) atomicMax(&hdr[4 + tid], sdyn[tid]);
}

__global__ void k_mfixed(const int* __restrict__ bits, char* ws) {
    unsigned* hdr = (unsigned*)ws;
    float* hf = (float*)ws;
    int tid = threadIdx.x;
    __shared__ float Mf[16], trs[16];
    if (tid < 16) {
        float dm = __uint_as_float(hdr[4 + tid]);
        int tr = (tid >= 1) ? ((1 << (tid - 1)) - 1) : 0;
        float M = 0.0f;
        if (dm > 0.0f) M = rintf(((float)tr / dm) * 65536.0f);
        Mf[tid] = M; trs[tid] = (float)tr;
    }
    __syncthreads();
    int oc = tid;  // 256 threads
    int g = bits[oc] & 15;
    hf[320 + oc] = Mf[g];
    hf[576 + oc] = -trs[g] - 1.0f;
    hf[832 + oc] = trs[g];
}

__global__ __launch_bounds__(256) void k_requant(float* __restrict__ out, char* ws) {
    const float* hf = (const float*)ws;
    float4* o4 = (float4*)out;
    const int n4 = N_X / 4;
    const float inv64k = 1.0f / 65536.0f;
    for (int i = blockIdx.x * blockDim.x + threadIdx.x; i < n4; i += gridDim.x * blockDim.x) {
        int oc = (int)(((i * 4) / 3136) & 255);   // 3136 px per (n,oc) plane, divisible by 4
        float M = hf[320 + oc], lo = hf[576 + oc], hi = hf[832 + oc];
        float4 v = o4[i];
        v.x = fminf(fmaxf(rintf(v.x * M * inv64k), lo), hi);
        v.y = fminf(fmaxf(rintf(v.y * M * inv64k), lo), hi);
        v.z = fminf(fmaxf(rintf(v.z * M * inv64k), lo), hi);
        v.w = fminf(fmaxf(rintf(v.w * M * inv64k), lo), hi);
        o4[i] = v;
    }
}

extern "C" void kernel_launch(void* const* d_in, const int* in_sizes, int n_in,
                              void* d_out, int out_size, void* d_ws, size_t ws_size,
                              hipStream_t stream) {
    const float* x      = (const float*)d_in[0];
    const float* weight = (const float*)d_in[1];
    const float* bias   = (const float*)d_in[2];
    const int*   bits   = (const int*)d_in[3];
    float* out = (float*)d_out;
    char* ws = (char*)d_ws;
    unsigned* hdr = (unsigned*)ws;

    // zero the padded quantized-x buffer (borders must be 0 each launch)
    hipMemsetAsync(ws + XP_OFF, 0, XP_ELEMS * 2, stream);
    k_init<<<1, 64, 0, stream>>>(hdr);
    k_minmax<<<2048, 256, 0, stream>>>((const float4*)x, N_X / 4, hdr);
    k_scalars<<<1, 1, 0, stream>>>(hdr);
    k_wquant<<<256, 256, 0, stream>>>(weight, bias, bits, ws);
    k_quantx<<<dim3(7, 56, 32), 256, 0, stream>>>(x, ws);
    k_conv<<<N_IMG * 56, 256, 0, stream>>>(bits, out, ws);
    k_mfixed<<<1, 256, 0, stream>>>(bits, ws);
    k_requant<<<2048, 256, 0, stream>>>(out, ws);
}

// Round 3
// 593.457 us; speedup vs baseline: 1.0372x; 1.0372x over previous
//
#include <hip/hip_runtime.h>
#include <hip/hip_bf16.h>

typedef float f32x4 __attribute__((ext_vector_type(4)));
typedef __bf16 bf16x8 __attribute__((ext_vector_type(8)));

#define N_IMG 32
#define C_IN  256
#define HW    56
#define N_X   (N_IMG * C_IN * HW * HW)
#define HP    58
#define WPAD  68

static constexpr size_t WQ_OFF  = 8192;                 // bf16[256][2304]  [oc][tap][c]
static constexpr size_t XP_OFF  = 2097152;              // bf16[32][58][68][256]

// header floats/uints in ws:
// [0] xmin_enc [1] xmax_enc [2] in_scale [3] zp
// [4..19] dynmax per bit value
// [64..319] b_int  [320..575] M  [576..831] lo  [832..1087] hi

__device__ __forceinline__ unsigned enc_f(float f) {
    unsigned u = __float_as_uint(f);
    return (u & 0x80000000u) ? ~u : (u | 0x80000000u);
}
__device__ __forceinline__ float dec_f(unsigned u) {
    u = (u & 0x80000000u) ? (u & 0x7FFFFFFFu) : ~u;
    return __uint_as_float(u);
}

__device__ __forceinline__ void gload16(void* lds, const void* g) {
    __builtin_amdgcn_global_load_lds(
        (const __attribute__((address_space(1))) unsigned int*)g,
        (__attribute__((address_space(3))) unsigned int*)lds, 16, 0, 0);
}

__global__ void k_init(unsigned* hdr) {
    int t = threadIdx.x;
    if (t == 0) hdr[0] = 0xFFFFFFFFu;
    if (t == 1) hdr[1] = 0u;
    if (t >= 4 && t < 20) hdr[t] = 0u;
}

__global__ __launch_bounds__(256) void k_minmax(const float4* __restrict__ x4, int n4, unsigned* hdr) {
    float mn = INFINITY, mx = -INFINITY;
    for (int i = blockIdx.x * blockDim.x + threadIdx.x; i < n4; i += gridDim.x * blockDim.x) {
        float4 v = x4[i];
        mn = fminf(mn, fminf(fminf(v.x, v.y), fminf(v.z, v.w)));
        mx = fmaxf(mx, fmaxf(fmaxf(v.x, v.y), fmaxf(v.z, v.w)));
    }
    for (int s = 32; s; s >>= 1) {
        mn = fminf(mn, __shfl_xor(mn, s));
        mx = fmaxf(mx, __shfl_xor(mx, s));
    }
    __shared__ float smn[4], smx[4];
    int l = threadIdx.x & 63, wv = threadIdx.x >> 6;
    if (l == 0) { smn[wv] = mn; smx[wv] = mx; }
    __syncthreads();
    if (threadIdx.x == 0) {
        mn = fminf(fminf(smn[0], smn[1]), fminf(smn[2], smn[3]));
        mx = fmaxf(fmaxf(smx[0], smx[1]), fmaxf(smx[2], smx[3]));
        atomicMin(&hdr[0], enc_f(mn));
        atomicMax(&hdr[1], enc_f(mx));
    }
}

__global__ void k_scalars(unsigned* hdr) {
    float xmin = dec_f(hdr[0]), xmax = dec_f(hdr[1]);
    float in_scale = (xmax - xmin) / 255.0f;
    float zp = rintf(-128.0f - xmin / in_scale);
    ((float*)hdr)[2] = in_scale;
    ((float*)hdr)[3] = zp;
}

__global__ __launch_bounds__(256) void k_wquant(const float* __restrict__ weight,
                                                const float* __restrict__ bias,
                                                const int* __restrict__ bits,
                                                char* ws) {
    float* hf = (float*)ws;
    __hip_bfloat16* Wq = (__hip_bfloat16*)(ws + WQ_OFF);
    int oc = blockIdx.x, tid = threadIdx.x;
    const float* wp = weight + ((size_t)oc * 256 + tid) * 9;
    float w9[9];
    float wm = 0.0f;
#pragma unroll
    for (int t = 0; t < 9; ++t) { w9[t] = wp[t]; wm = fmaxf(wm, fabsf(w9[t])); }
    for (int s = 32; s; s >>= 1) wm = fmaxf(wm, __shfl_xor(wm, s));
    __shared__ float red[4];
    __shared__ float s_wsc;
    int l = tid & 63, wv = tid >> 6;
    if (l == 0) red[wv] = wm;
    __syncthreads();
    int b = bits[oc];
    if (tid == 0) {
        float wmax = fmaxf(fmaxf(red[0], red[1]), fmaxf(red[2], red[3]));
        float qd = (float)((1 << b) - 1);
        float wsc = fmaxf(wmax * 2.0f / qd, 1e-9f);
        s_wsc = wsc;
        float in_scale = hf[2];
        hf[64 + oc] = rintf(bias[oc] / (in_scale * wsc));
    }
    __syncthreads();
    float wsc = s_wsc;
    float qmax = (float)((1 << (b - 1)) - 1);
    float qmin = -(float)(1 << (b - 1));
    size_t base = (size_t)oc * 2304;
#pragma unroll
    for (int t = 0; t < 9; ++t) {
        float q = rintf(w9[t] / wsc);
        q = fminf(fmaxf(q, qmin), qmax);
        Wq[base + t * 256 + tid] = __float2bfloat16(q);
    }
}

// quantize + NCHW -> padded NHWC bf16; writes borders (zeros) too, so no memset needed
__global__ __launch_bounds__(256) void k_quantx(const float* __restrict__ x, char* ws) {
    const float* hf = (const float*)ws;
    float in_scale = hf[2], zp = hf[3];
    __hip_bfloat16* Xp = (__hip_bfloat16*)(ws + XP_OFF);
    int w0 = blockIdx.x * 64, h = blockIdx.y, n = blockIdx.z;   // h,wp are PADDED coords
    int tid = threadIdx.x;
    __shared__ float tx[32][65];
    int wA = tid & 63, cA = tid >> 6;      // read: 64 w x 4 c (one c per wave)
    int wW = tid >> 2, cq = tid & 3;       // write: 64 w x 4 c-octs
    int xh = h - 1;
    bool hok = (xh >= 0 && xh < 56);
    int xw = w0 + wA - 1;
    bool wok = (xw >= 0 && xw < 56);
    for (int ct = 0; ct < 8; ++ct) {
#pragma unroll
        for (int cs = 0; cs < 8; ++cs) {
            int c = ct * 32 + cs * 4 + cA;
            float q = 0.0f;
            if (hok && wok) {
                float v = x[(((size_t)n * 256 + c) * 56 + xh) * 56 + xw];
                float xi = rintf(v / in_scale + zp);
                xi = fminf(fmaxf(xi, -128.0f), 127.0f);
                q = xi - zp;
            }
            tx[cs * 4 + cA][wA] = q;
        }
        __syncthreads();
        if (w0 + wW < WPAD) {
            __hip_bfloat16 tmp[8];
#pragma unroll
            for (int k2 = 0; k2 < 8; ++k2) tmp[k2] = __float2bfloat16(tx[cq * 8 + k2][wW]);
            *(uint4*)&Xp[(((size_t)n * HP + h) * WPAD + w0 + wW) * 256 + ct * 32 + cq * 8] =
                *(uint4*)tmp;
        }
        __syncthreads();
    }
}

// conv: workgroup = 256 oc x 2 output rows (2x64 px); 4 waves = 2 oc-halves x 2 rows
// K-loop: 4 iters of 64 channels; stages 4 input rows x 68 wp x 64 c via global_load_lds,
// double-buffered. LDS layout linear [row][wp][64c] with oct ^= (wp&7) pre-swizzled at the
// global source (both-sides swizzle) -> conflict-free ds_read_b128.
__global__ __launch_bounds__(256, 2) void k_conv(const int* __restrict__ bits,
                                                 float* __restrict__ out, char* ws) {
    const float* hf = (const float*)ws;
    unsigned* hdr = (unsigned*)ws;
    const __hip_bfloat16* Xp = (const __hip_bfloat16*)(ws + XP_OFF);
    const bf16x8* wq8 = (const bf16x8*)(ws + WQ_OFF);

    int bid = blockIdx.x;
    int wg = (bid & 7) * 112 + (bid >> 3);     // XCD swizzle (896 % 8 == 0, bijective)
    int n = wg / 28, h0 = (wg % 28) * 2;

    int tid = threadIdx.x;
    int wv = tid >> 6, l = tid & 63;
    int l15 = l & 15, lq = l >> 4;
    int oc0 = (wv >> 1) * 128;                 // oc half
    int orow = wv & 1;                         // output row within pair

    __shared__ __hip_bfloat16 Xs[2 * 17408];   // 2 x [4][68][64] bf16 = 2 x 34816 B
    __shared__ unsigned sdyn[16];
    if (tid < 16) sdyn[tid] = 0;

    // staging precompute: chunk = k*256 + tid -> (row, wp, oct) with source-side swizzle
    int soff[9];
#pragma unroll
    for (int k = 0; k < 9; ++k) {
        int chunk = k * 256 + tid;             // 544 chunks per row (68 wp x 8 octs)
        int row = chunk / 544;
        int rem = chunk - row * 544;
        int wp = rem >> 3, u = rem & 7;
        int oct = u ^ (wp & 7);
        soff[k] = (row * WPAD + wp) * 256 + oct * 8;
    }
    int wavebase = tid & 192;
    size_t imgbase = ((size_t)n * HP + h0) * (size_t)(WPAD * 256);

    f32x4 acc[8][4];
#pragma unroll
    for (int i = 0; i < 8; ++i)
#pragma unroll
        for (int j = 0; j < 4; ++j) acc[i][j] = (f32x4){0.f, 0.f, 0.f, 0.f};

    auto STAGE = [&](int bufsel, int it) {
        const __hip_bfloat16* gb = Xp + imgbase + it * 64;
        char* lb = (char*)Xs + bufsel * 34816;
#pragma unroll
        for (int k = 0; k < 9; ++k) {
            if (k < 8 || tid < 128) {
                gload16(lb + (k * 256 + wavebase) * 16, gb + soff[k]);
            }
        }
    };

    STAGE(0, 0);
    __syncthreads();
    int buf = 0;
#pragma unroll 1
    for (int it = 0; it < 4; ++it) {
        if (it < 3) STAGE(buf ^ 1, it + 1);
        const __hip_bfloat16* Xb = Xs + buf * 17408;
#pragma unroll
        for (int dh = 0; dh < 3; ++dh) {
            int row = orow + dh;
#pragma unroll
            for (int dw = 0; dw < 3; ++dw) {
                int tap = dh * 3 + dw;
#pragma unroll
                for (int ks = 0; ks < 2; ++ks) {
                    bf16x8 af[8];
#pragma unroll
                    for (int i = 0; i < 8; ++i)
                        af[i] = wq8[(size_t)(oc0 + i * 16 + l15) * 288 + tap * 32 +
                                    it * 8 + ks * 4 + lq];
#pragma unroll
                    for (int j = 0; j < 4; ++j) {
                        int wp = j * 16 + l15 + dw;
                        int u = (ks * 4 + lq) ^ (wp & 7);
                        bf16x8 bv = *(const bf16x8*)&Xb[((row * 68 + wp) * 8 + u) * 8];
#pragma unroll
                        for (int i = 0; i < 8; ++i)
                            acc[i][j] = __builtin_amdgcn_mfma_f32_16x16x32_bf16(
                                af[i], bv, acc[i][j], 0, 0, 0);
                    }
                }
            }
        }
        __syncthreads();
        buf ^= 1;
    }

    // epilogue: + b_int, store, per-group max|acc|
    int hrow = h0 + orow;
#pragma unroll
    for (int i = 0; i < 8; ++i) {
#pragma unroll
        for (int r = 0; r < 4; ++r) {
            int oc = oc0 + i * 16 + lq * 4 + r;
            float bi = hf[64 + oc];
            float m = 0.0f;
#pragma unroll
            for (int j = 0; j < 4; ++j) {
                int w = j * 16 + l15;
                float v = acc[i][j][r] + bi;
                if (w < 56) {
                    out[(((size_t)n * 256 + oc) * 56 + hrow) * 56 + w] = v;
                    m = fmaxf(m, fabsf(v));
                }
            }
#pragma unroll
            for (int s = 1; s < 16; s <<= 1) m = fmaxf(m, __shfl_xor(m, s));
            if (l15 == 0) atomicMax(&sdyn[bits[oc] & 15], __float_as_uint(m));
        }
    }
    __syncthreads();
    if (tid < 16 && sdyn[tid]) atomicMax(&hdr[4 + tid], sdyn[tid]);
}

__global__ void k_mfixed(const int* __restrict__ bits, char* ws) {
    unsigned* hdr = (unsigned*)ws;
    float* hf = (float*)ws;
    int tid = threadIdx.x;
    __shared__ float Mf[16], trs[16];
    if (tid < 16) {
        float dm = __uint_as_float(hdr[4 + tid]);
        int tr = (tid >= 1) ? ((1 << (tid - 1)) - 1) : 0;
        float M = 0.0f;
        if (dm > 0.0f) M = rintf(((float)tr / dm) * 65536.0f);
        Mf[tid] = M; trs[tid] = (float)tr;
    }
    __syncthreads();
    int oc = tid;
    int g = bits[oc] & 15;
    hf[320 + oc] = Mf[g];
    hf[576 + oc] = -trs[g] - 1.0f;
    hf[832 + oc] = trs[g];
}

__global__ __launch_bounds__(256) void k_requant(float* __restrict__ out, char* ws) {
    const float* hf = (const float*)ws;
    float4* o4 = (float4*)out;
    const int n4 = N_X / 4;
    const float inv64k = 1.0f / 65536.0f;
    for (int i = blockIdx.x * blockDim.x + threadIdx.x; i < n4; i += gridDim.x * blockDim.x) {
        int oc = (int)(((i * 4) / 3136) & 255);
        float M = hf[320 + oc], lo = hf[576 + oc], hi = hf[832 + oc];
        float4 v = o4[i];
        v.x = fminf(fmaxf(rintf(v.x * M * inv64k), lo), hi);
        v.y = fminf(fmaxf(rintf(v.y * M * inv64k), lo), hi);
        v.z = fminf(fmaxf(rintf(v.z * M * inv64k), lo), hi);
        v.w = fminf(fmaxf(rintf(v.w * M * inv64k), lo), hi);
        o4[i] = v;
    }
}

extern "C" void kernel_launch(void* const* d_in, const int* in_sizes, int n_in,
                              void* d_out, int out_size, void* d_ws, size_t ws_size,
                              hipStream_t stream) {
    const float* x      = (const float*)d_in[0];
    const float* weight = (const float*)d_in[1];
    const float* bias   = (const float*)d_in[2];
    const int*   bits   = (const int*)d_in[3];
    float* out = (float*)d_out;
    char* ws = (char*)d_ws;
    unsigned* hdr = (unsigned*)ws;

    k_init<<<1, 64, 0, stream>>>(hdr);
    k_minmax<<<2048, 256, 0, stream>>>((const float4*)x, N_X / 4, hdr);
    k_scalars<<<1, 1, 0, stream>>>(hdr);
    k_wquant<<<256, 256, 0, stream>>>(weight, bias, bits, ws);
    k_quantx<<<dim3(2, 58, 32), 256, 0, stream>>>(x, ws);
    k_conv<<<896, 256, 0, stream>>>(bits, out, ws);
    k_mfixed<<<1, 256, 0, stream>>>(bits, ws);
    k_requant<<<4096, 256, 0, stream>>>(out, ws);
}